// Round 1
// baseline (1801.728 us; speedup 1.0000x reference)
//
#include <hip/hip_runtime.h>

#define N_LAT 16384
#define N_EMB 16384
#define DIM   256
#define XQ_ELEMS (N_LAT * DIM)   // 4194304

// ---------------- workspace layout ----------------
// [0]      float  enorm[16384]    (64 KB)
// [65536]  u64    best[16384]     (128 KB)  init 0xFF
// [196608] int    hist[16384]     (64 KB)   init 0x00
// [262144] double bsum[16384]     (128 KB)  written unconditionally
// total: 393216 bytes

// ---- Kernel A: embed row squared norms, fp64 accumulate for accuracy ----
__global__ __launch_bounds__(256) void k_enorm(const float* __restrict__ embed,
                                               float* __restrict__ enorm) {
    const int gid  = blockIdx.x * 256 + threadIdx.x;
    const int wave = gid >> 6;            // 1024 waves total (grid 256)
    const int lane = threadIdx.x & 63;
    for (int row = wave; row < N_EMB; row += 1024) {
        const float4 v = *reinterpret_cast<const float4*>(&embed[row * DIM + lane * 4]);
        double s = (double)v.x * v.x + (double)v.y * v.y +
                   (double)v.z * v.z + (double)v.w * v.w;
#pragma unroll
        for (int m = 32; m; m >>= 1) s += __shfl_xor(s, m, 64);
        if (lane == 0) enorm[row] = (float)s;
    }
}

// ---- Kernel B: fused fp32 GEMM + argmin over codes ----
// grid: (128 row-blocks, 16 code-chunks), 256 threads.
// Each block: 128 rows x 1024 codes, BK=32 over d=256.
__global__ __launch_bounds__(256) void k_argmin(const float* __restrict__ x,
                                                const float* __restrict__ embed,
                                                const float* __restrict__ enorm,
                                                unsigned long long* __restrict__ best) {
    __shared__ float As[32][128];   // transposed: As[k][row]
    __shared__ float Bs[32][128];   // transposed: Bs[k][col]

    const int tid  = threadIdx.x;
    const int row0 = blockIdx.x * 128;
    const int kc   = blockIdx.y;            // 0..15
    const int tx   = tid & 15, ty = tid >> 4;
    const int r_lo = ty * 4, r_hi = 64 + ty * 4;
    const int c_lo = tx * 4, c_hi = 64 + tx * 4;

    float rmin[8];
    int   ridx[8];
#pragma unroll
    for (int i = 0; i < 8; ++i) { rmin[i] = 3.402823e38f; ridx[i] = 0; }

    for (int ct = 0; ct < 8; ++ct) {            // 8 code tiles of 128
        const int col0 = kc * 1024 + ct * 128;
        float acc[8][8];
#pragma unroll
        for (int i = 0; i < 8; ++i)
#pragma unroll
            for (int j = 0; j < 8; ++j) acc[i][j] = 0.0f;

        for (int d0 = 0; d0 < DIM; d0 += 32) {
            __syncthreads();                    // protect LDS from previous iter
            // stage 128x32 A and B tiles (transposed into LDS)
#pragma unroll
            for (int j = 0; j < 4; ++j) {
                const int f = tid + 256 * j;    // 0..1023 float4 id
                const int r = f >> 3, c = f & 7;
                const float4 va = *reinterpret_cast<const float4*>(
                    &x[(size_t)(row0 + r) * DIM + d0 + c * 4]);
                As[c * 4 + 0][r] = va.x; As[c * 4 + 1][r] = va.y;
                As[c * 4 + 2][r] = va.z; As[c * 4 + 3][r] = va.w;
                const float4 vb = *reinterpret_cast<const float4*>(
                    &embed[(size_t)(col0 + r) * DIM + d0 + c * 4]);
                Bs[c * 4 + 0][r] = vb.x; Bs[c * 4 + 1][r] = vb.y;
                Bs[c * 4 + 2][r] = vb.z; Bs[c * 4 + 3][r] = vb.w;
            }
            __syncthreads();
#pragma unroll
            for (int kk = 0; kk < 32; ++kk) {
                float a[8], b[8];
                *reinterpret_cast<float4*>(&a[0]) = *reinterpret_cast<const float4*>(&As[kk][r_lo]);
                *reinterpret_cast<float4*>(&a[4]) = *reinterpret_cast<const float4*>(&As[kk][r_hi]);
                *reinterpret_cast<float4*>(&b[0]) = *reinterpret_cast<const float4*>(&Bs[kk][c_lo]);
                *reinterpret_cast<float4*>(&b[4]) = *reinterpret_cast<const float4*>(&Bs[kk][c_hi]);
#pragma unroll
                for (int i = 0; i < 8; ++i)
#pragma unroll
                    for (int j = 0; j < 8; ++j)
                        acc[i][j] = fmaf(a[i], b[j], acc[i][j]);
            }
        }
        // epilogue: dist = ||e||^2 - 2*dot ; running argmin (cols ascending -> first-min tie-break)
#pragma unroll
        for (int j = 0; j < 8; ++j) {
            const int col = col0 + (j < 4 ? c_lo + j : c_hi + (j - 4));
            const float s = enorm[col];
#pragma unroll
            for (int i = 0; i < 8; ++i) {
                const float v = fmaf(-2.0f, acc[i][j], s);
                if (v < rmin[i]) { rmin[i] = v; ridx[i] = col; }
            }
        }
    }
    // reduce across the 16 tx lanes sharing each row, then one atomic per row
#pragma unroll
    for (int i = 0; i < 8; ++i) {
        unsigned u = __float_as_uint(rmin[i]);
        u = (u & 0x80000000u) ? ~u : (u | 0x80000000u);   // monotonic float->uint
        unsigned long long p = ((unsigned long long)u << 32) | (unsigned)ridx[i];
#pragma unroll
        for (int m = 1; m < 16; m <<= 1) {
            const unsigned long long q = __shfl_xor(p, m, 64);
            p = (q < p) ? q : p;
        }
        if (tx == 0) {
            const int row = row0 + (i < 4 ? r_lo + i : r_hi + (i - 4));
            atomicMin(&best[row], p);
        }
    }
}

// ---- Kernel C: gather x_q, STE output, per-block SSE, usage histogram, indices ----
__global__ __launch_bounds__(256) void k_gather(const float* __restrict__ x,
                                                const float* __restrict__ embed,
                                                const unsigned long long* __restrict__ best,
                                                float* __restrict__ out,
                                                int* __restrict__ hist,
                                                double* __restrict__ bsum) {
    __shared__ double partial[4];
    const int row = blockIdx.x;
    const int t   = threadIdx.x;
    const int idx = (int)(best[row] & 0xFFFFFFFFULL);
    const float e  = embed[(size_t)idx * DIM + t];
    const float xv = x[(size_t)row * DIM + t];
    const float d  = e - xv;                 // x_q - x (reference rounding)
    out[(size_t)row * DIM + t] = xv + d;     // x + (x_q - x): bitwise-matches STE
    double sq = (double)d * (double)d;
#pragma unroll
    for (int m = 32; m; m >>= 1) sq += __shfl_xor(sq, m, 64);
    const int lane = t & 63, w = t >> 6;
    if (lane == 0) partial[w] = sq;
    __syncthreads();
    if (t == 0) {
        bsum[row] = partial[0] + partial[1] + partial[2] + partial[3];
        atomicAdd(&hist[idx], 1);
        out[XQ_ELEMS + 2 + row] = (float)idx;   // embed_ind as float
    }
}

// ---- Kernel D: finalize scalars ----
__global__ __launch_bounds__(256) void k_final(const int* __restrict__ hist,
                                               const double* __restrict__ bsum,
                                               float* __restrict__ out) {
    __shared__ int    cpart[4];
    __shared__ double spart[4];
    const int t = threadIdx.x;
    int cnt = 0; double s = 0.0;
    for (int i = t; i < N_EMB; i += 256) {
        cnt += (hist[i] == 0) ? 1 : 0;
        s += bsum[i];
    }
#pragma unroll
    for (int m = 32; m; m >>= 1) {
        cnt += __shfl_xor(cnt, m, 64);
        s   += __shfl_xor(s, m, 64);
    }
    const int lane = t & 63, w = t >> 6;
    if (lane == 0) { cpart[w] = cnt; spart[w] = s; }
    __syncthreads();
    if (t == 0) {
        const double sse = spart[0] + spart[1] + spart[2] + spart[3];
        out[XQ_ELEMS + 0] = (float)(1.25 * sse / (double)XQ_ELEMS);   // quant_loss
        out[XQ_ELEMS + 1] = (float)(cpart[0] + cpart[1] + cpart[2] + cpart[3]); // unused
    }
}

extern "C" void kernel_launch(void* const* d_in, const int* in_sizes, int n_in,
                              void* d_out, int out_size, void* d_ws, size_t ws_size,
                              hipStream_t stream) {
    const float* x     = (const float*)d_in[0];   // 128*128*256
    const float* embed = (const float*)d_in[1];   // 16384*256
    float* out = (float*)d_out;

    char* ws = (char*)d_ws;
    float*              enorm = (float*)(ws + 0);
    unsigned long long* best  = (unsigned long long*)(ws + 65536);
    int*                hist  = (int*)(ws + 196608);
    double*             bsum  = (double*)(ws + 262144);

    hipMemsetAsync(best, 0xFF, N_LAT * sizeof(unsigned long long), stream);
    hipMemsetAsync(hist, 0x00, N_EMB * sizeof(int), stream);

    k_enorm <<<256, 256, 0, stream>>>(embed, enorm);
    k_argmin<<<dim3(128, 16), 256, 0, stream>>>(x, embed, enorm, best);
    k_gather<<<N_LAT, 256, 0, stream>>>(x, embed, best, out, hist, bsum);
    k_final <<<1, 256, 0, stream>>>(hist, bsum, out);
}